// Round 2
// baseline (611.498 us; speedup 1.0000x reference)
//
#include <hip/hip_runtime.h>

#define F 3
#define V 512
#define D 8192
#define B 64
#define ITERS 10

typedef __bf16 bf16_t;
typedef __bf16 bf16x8 __attribute__((ext_vector_type(8)));
typedef __bf16 bf16x4 __attribute__((ext_vector_type(4)));
typedef float f32x4 __attribute__((ext_vector_type(4)));

// ---------------------------------------------------------------------------
// init (elementwise): Cb = bf16(codebooks), est0 = bf16(init_estimates),
// zero sim buffers + anydiff flags
// ---------------------------------------------------------------------------
__global__ void k_init_ew(const float* __restrict__ cod, const float* __restrict__ ie,
                          bf16_t* __restrict__ Cb, bf16_t* __restrict__ est0,
                          float* __restrict__ simBase, int* __restrict__ anydiff) {
  long tid = (long)blockIdx.x * blockDim.x + threadIdx.x;
  long NT  = (long)gridDim.x * blockDim.x;
  for (long i = tid * 4; i < (long)F * V * D; i += NT * 4) {
    f32x4 x = *(const f32x4*)(cod + i);
    bf16x4 y;
    y[0] = (bf16_t)x[0]; y[1] = (bf16_t)x[1]; y[2] = (bf16_t)x[2]; y[3] = (bf16_t)x[3];
    *(bf16x4*)(Cb + i) = y;
  }
  for (long i = tid * 4; i < (long)B * F * D; i += NT * 4) {
    f32x4 x = *(const f32x4*)(ie + i);
    bf16x4 y;
    y[0] = (bf16_t)x[0]; y[1] = (bf16_t)x[1]; y[2] = (bf16_t)x[2]; y[3] = (bf16_t)x[3];
    *(bf16x4*)(est0 + i) = y;
  }
  f32x4 z = {0.f, 0.f, 0.f, 0.f};
  for (long i = tid * 4; i < (long)(ITERS + 1) * F * B * V; i += NT * 4)
    *(f32x4*)(simBase + i) = z;
  if (tid < 16) anydiff[tid] = 0;
}

// ---------------------------------------------------------------------------
// init (transpose): CbT[f][d][v] = bf16(codebooks[f][v][d])
// ---------------------------------------------------------------------------
__global__ __launch_bounds__(256) void k_init_tr(const float* __restrict__ Csrc,
                                                 bf16_t* __restrict__ CbT) {
  int f = blockIdx.z, vt = blockIdx.y, dt = blockIdx.x;
  __shared__ bf16_t tile[64 * 65];
  int t = threadIdx.x;
  int v0 = vt * 64, d0 = dt * 64;
#pragma unroll
  for (int p = 0; p < 16; ++p) {
    int q = t + 256 * p;
    int i = q >> 6, j = q & 63;
    tile[i * 65 + j] = (bf16_t)Csrc[((long)(f * V + v0 + i)) * D + d0 + j];
  }
  __syncthreads();
#pragma unroll
  for (int p = 0; p < 16; ++p) {
    int q = t + 256 * p;
    int jj = q >> 6, ii = q & 63;
    CbT[((long)f * D + d0 + jj) * V + v0 + ii] = tile[ii * 65 + jj];
  }
}

// ---------------------------------------------------------------------------
// kernel A: sim[f][b][v] += sum_d A[b,f,d] * C[f][v][d]
//   iter < ITERS : A = newest = inputs * est_f1 * est_f2   (iteration step)
//   iter == ITERS: A = est itself                          (final projection!)
// grid (8 ksplit, 8 vtiles, 3 f) x 256 threads. Exact integer arithmetic.
// ---------------------------------------------------------------------------
__global__ __launch_bounds__(256) void k_sim(const float* __restrict__ inputs,
                                             const bf16_t* __restrict__ Cb,
                                             const bf16_t* __restrict__ est0,
                                             const bf16_t* __restrict__ est1,
                                             float* __restrict__ simBase,
                                             const int* __restrict__ anydiff, int iter) {
  const int f = blockIdx.z, vt = blockIdx.y, ks = blockIdx.x;
  const bf16_t* est;
  float* sim;
  const bool is_final = (iter >= ITERS);
  if (is_final) {
    int first0 = ITERS;
    for (int i = 0; i < ITERS; ++i) {
      if (anydiff[i] == 0) { first0 = i; break; }
    }
    int par = (first0 < ITERS) ? ((first0 + 1) & 1) : 0;
    est = par ? est1 : est0;
    sim = simBase + (long)ITERS * (F * B * V);
  } else {
    for (int i = 0; i < iter; ++i)
      if (anydiff[i] == 0) return;  // converged earlier: uniform exit
    est = (iter & 1) ? est1 : est0;
    sim = simBase + (long)iter * (F * B * V);
  }
  const int f1 = (f + 1) % 3, f2 = (f + 2) % 3;

  __shared__ __attribute__((aligned(16))) bf16_t lA[64 * 88];  // [b][d]
  __shared__ __attribute__((aligned(16))) bf16_t lB[64 * 88];  // [v][d]

  const int t = threadIdx.x;
  const int lane = t & 63, w = t >> 6;
  const int lm = lane & 15, quad = lane >> 4;

  f32x4 zero = {0.f, 0.f, 0.f, 0.f};
  f32x4 acc[4];
#pragma unroll
  for (int mt = 0; mt < 4; ++mt) acc[mt] = zero;

  const int v0 = vt * 64;
  const int dbase = ks * 1024;

  for (int c = 0; c < 16; ++c) {
    const int d0 = dbase + c * 64;
    __syncthreads();
    // stage A tile: 64 b x 64 d
#pragma unroll
    for (int p = 0; p < 2; ++p) {
      int q = t + 256 * p;
      int b = q >> 3, dd = (q & 7) * 8;
      if (is_final) {
        *(bf16x8*)&lA[b * 88 + dd] =
            *(const bf16x8*)(est + ((long)b * F + f) * D + d0 + dd);
      } else {
        const float* ip = inputs + (long)b * D + d0 + dd;
        bf16x8 e1 = *(const bf16x8*)(est + ((long)b * F + f1) * D + d0 + dd);
        bf16x8 e2 = *(const bf16x8*)(est + ((long)b * F + f2) * D + d0 + dd);
        bf16x8 o;
#pragma unroll
        for (int i = 0; i < 8; ++i)
          o[i] = (bf16_t)(ip[i] * (float)e1[i] * (float)e2[i]);
        *(bf16x8*)&lA[b * 88 + dd] = o;
      }
    }
    // stage B tile: codebook rows (natural layout = n-major/k-contiguous)
#pragma unroll
    for (int p = 0; p < 2; ++p) {
      int q = t + 256 * p;
      int v = q >> 3, dd = (q & 7) * 8;
      *(bf16x8*)&lB[v * 88 + dd] =
          *(const bf16x8*)(Cb + ((long)(f * V + v0 + v)) * D + d0 + dd);
    }
    __syncthreads();
#pragma unroll
    for (int ks2 = 0; ks2 < 2; ++ks2) {
      const int kb = ks2 * 32 + quad * 8;
      bf16x8 bfrag = *(const bf16x8*)&lB[(w * 16 + lm) * 88 + kb];
#pragma unroll
      for (int mt = 0; mt < 4; ++mt) {
        bf16x8 afrag = *(const bf16x8*)&lA[(mt * 16 + lm) * 88 + kb];
        acc[mt] = __builtin_amdgcn_mfma_f32_16x16x32_bf16(afrag, bfrag, acc[mt], 0, 0, 0);
      }
    }
  }
  const int v = v0 + w * 16 + lm;
#pragma unroll
  for (int mt = 0; mt < 4; ++mt)
#pragma unroll
    for (int r = 0; r < 4; ++r) {
      int b = mt * 16 + quad * 4 + r;
      atomicAdd(&sim[(f * B + b) * V + v], acc[mt][r]);
    }
}

// ---------------------------------------------------------------------------
// kernel B: est' = sign(sim . C) with exact 256*h + l bf16 split + conv flag
// grid (64 dtiles, 3 f) x 256 threads. M=64 N=128 K=512.
// ---------------------------------------------------------------------------
__global__ __launch_bounds__(256) void k_upd(const float* __restrict__ simBase,
                                             const bf16_t* __restrict__ CbT,
                                             bf16_t* __restrict__ est0,
                                             bf16_t* __restrict__ est1,
                                             int* __restrict__ anydiff, int iter) {
  const int f = blockIdx.y;
  const int d0 = blockIdx.x * 128;
  for (int i = 0; i < iter; ++i)
    if (anydiff[i] == 0) return;
  const bf16_t* estIn = (iter & 1) ? est1 : est0;
  bf16_t* estOut = (iter & 1) ? est0 : est1;
  const float* sim = simBase + (long)iter * (F * B * V) + f * (B * V);

  __shared__ __attribute__((aligned(16))) bf16_t lAh[64 * 88];   // [b][v]
  __shared__ __attribute__((aligned(16))) bf16_t lAl[64 * 88];   // [b][v]
  __shared__ __attribute__((aligned(16))) bf16_t lB[128 * 88];   // [d][v]

  const int t = threadIdx.x;
  const int lane = t & 63, w = t >> 6;
  const int lm = lane & 15, quad = lane >> 4;

  f32x4 zero = {0.f, 0.f, 0.f, 0.f};
  f32x4 accH[4][2], accL[4][2];
#pragma unroll
  for (int mt = 0; mt < 4; ++mt)
#pragma unroll
    for (int nt = 0; nt < 2; ++nt) { accH[mt][nt] = zero; accL[mt][nt] = zero; }

  for (int c = 0; c < 8; ++c) {
    const int vb = c * 64;
    __syncthreads();
#pragma unroll
    for (int p = 0; p < 2; ++p) {
      int q = t + 256 * p;
      int b = q >> 3, vv = (q & 7) * 8;
      const float* sp = sim + b * V + vb + vv;
#pragma unroll
      for (int i = 0; i < 8; ++i) {
        int si = (int)sp[i];
        lAh[b * 88 + vv + i] = (bf16_t)(float)(si >> 8);
        lAl[b * 88 + vv + i] = (bf16_t)(float)(si & 255);
      }
    }
#pragma unroll
    for (int p = 0; p < 4; ++p) {
      int q = t + 256 * p;
      int r = q >> 3, vv = (q & 7) * 8;
      *(bf16x8*)&lB[r * 88 + vv] =
          *(const bf16x8*)(CbT + ((long)f * D + d0 + r) * V + vb + vv);
    }
    __syncthreads();
#pragma unroll
    for (int ks2 = 0; ks2 < 2; ++ks2) {
      const int kb = ks2 * 32 + quad * 8;
      bf16x8 bf0 = *(const bf16x8*)&lB[(w * 32 + lm) * 88 + kb];
      bf16x8 bf1 = *(const bf16x8*)&lB[(w * 32 + 16 + lm) * 88 + kb];
#pragma unroll
      for (int mt = 0; mt < 4; ++mt) {
        bf16x8 ah = *(const bf16x8*)&lAh[(mt * 16 + lm) * 88 + kb];
        bf16x8 al = *(const bf16x8*)&lAl[(mt * 16 + lm) * 88 + kb];
        accH[mt][0] = __builtin_amdgcn_mfma_f32_16x16x32_bf16(ah, bf0, accH[mt][0], 0, 0, 0);
        accH[mt][1] = __builtin_amdgcn_mfma_f32_16x16x32_bf16(ah, bf1, accH[mt][1], 0, 0, 0);
        accL[mt][0] = __builtin_amdgcn_mfma_f32_16x16x32_bf16(al, bf0, accL[mt][0], 0, 0, 0);
        accL[mt][1] = __builtin_amdgcn_mfma_f32_16x16x32_bf16(al, bf1, accL[mt][1], 0, 0, 0);
      }
    }
  }
  bool anyd = false;
#pragma unroll
  for (int mt = 0; mt < 4; ++mt)
#pragma unroll
    for (int nt = 0; nt < 2; ++nt)
#pragma unroll
      for (int r = 0; r < 4; ++r) {
        int b = mt * 16 + quad * 4 + r;
        int d = d0 + w * 32 + nt * 16 + lm;
        float val = 256.f * accH[mt][nt][r] + accL[mt][nt][r];
        float s = (val > 0.f) ? 1.f : ((val < 0.f) ? -1.f : 0.f);
        long idx = ((long)b * F + f) * D + d;
        estOut[idx] = (bf16_t)s;
        anyd |= ((float)estIn[idx] != s);
      }
  if (__any(anyd) && lane == 0) atomicOr(&anydiff[iter], 1);
}

// ---------------------------------------------------------------------------
// final: argmax over V per (b,f) (first-max tie-break) + iteration count
// ---------------------------------------------------------------------------
__global__ __launch_bounds__(64) void k_out(const float* __restrict__ simBase,
                                            const int* __restrict__ anydiff,
                                            int* __restrict__ out) {
  const float* sim = simBase + (long)ITERS * (F * B * V);
  int bid = blockIdx.x;  // 0..191
  int b = bid / F, f = bid % F;
  int lane = threadIdx.x;
  const float* row = sim + (f * B + b) * V;
  float best = -1e30f;
  int bidx = 0;
#pragma unroll
  for (int i = 0; i < V / 64; ++i) {
    int v = lane + 64 * i;  // ascending within lane -> strict > keeps first max
    float x = row[v];
    if (x > best) { best = x; bidx = v; }
  }
  for (int off = 32; off; off >>= 1) {
    float ov = __shfl_down(best, off, 64);
    int oi = __shfl_down(bidx, off, 64);
    if (ov > best || (ov == best && oi < bidx)) { best = ov; bidx = oi; }
  }
  if (lane == 0) out[b * F + f] = bidx;
  if (bid == 0 && lane == 0) {
    int first0 = ITERS;
    for (int i = 0; i < ITERS; ++i) {
      if (anydiff[i] == 0) { first0 = i; break; }
    }
    int cnt = (first0 < ITERS) ? (first0 + 1) : ITERS;
    out[B * F] = cnt - 1;
  }
}

// ---------------------------------------------------------------------------
extern "C" void kernel_launch(void* const* d_in, const int* in_sizes, int n_in,
                              void* d_out, int out_size, void* d_ws, size_t ws_size,
                              hipStream_t stream) {
  const float* inputs    = (const float*)d_in[0];  // (B, D)
  const float* init_est  = (const float*)d_in[1];  // (B, F, D)
  const float* codebooks = (const float*)d_in[2];  // (F, V, D)

  char* w = (char*)d_ws;
  size_t o = 0;
  auto alloc = [&](size_t bytes) -> void* {
    void* p = w + o;
    o = (o + bytes + 255) & ~(size_t)255;
    return p;
  };
  bf16_t* Cb   = (bf16_t*)alloc((size_t)F * V * D * 2);
  bf16_t* CbT  = (bf16_t*)alloc((size_t)F * D * V * 2);
  bf16_t* est0 = (bf16_t*)alloc((size_t)B * F * D * 2);
  bf16_t* est1 = (bf16_t*)alloc((size_t)B * F * D * 2);
  float* simBase = (float*)alloc((size_t)(ITERS + 1) * F * B * V * 4);
  int* anydiff = (int*)alloc(64);

  k_init_ew<<<2048, 256, 0, stream>>>(codebooks, init_est, Cb, est0, simBase, anydiff);
  k_init_tr<<<dim3(128, 8, 3), 256, 0, stream>>>(codebooks, CbT);

  for (int j = 0; j < ITERS; ++j) {
    k_sim<<<dim3(8, 8, 3), 256, 0, stream>>>(inputs, Cb, est0, est1, simBase, anydiff, j);
    k_upd<<<dim3(64, 3), 256, 0, stream>>>(simBase, CbT, est0, est1, anydiff, j);
  }
  k_sim<<<dim3(8, 8, 3), 256, 0, stream>>>(inputs, Cb, est0, est1, simBase, anydiff, ITERS);
  k_out<<<B * F, 64, 0, stream>>>(simBase, anydiff, (int*)d_out);
}